// Round 1
// baseline (533.332 us; speedup 1.0000x reference)
//
#include <hip/hip_runtime.h>
#include <hip/hip_bf16.h>
#include <math.h>

// Problem: V=32000, D_REAL=768, D_HID=512, D_MODEL=4096, B*S=8192 tokens.
// out[t] = w2 @ elu(ln(w1 @ real[ids[t]])) + llama_embed[ids[t]]
// Only the 8192 gathered rows are ever needed -> compute per-token, not per-vocab-row.

#define TOKENS 8192
#define D_REAL 768
#define D_HID  512
#define D_MODEL 4096

// ---------------------------------------------------------------------------
// Tiled fp32 GEMM, C[M,N] = A[M,K] * B[N,K]^T  (both operands K-major).
// BM=BN=128, BK=16, 256 threads, 8x8 microtile per thread.
// GATHER_A: A row r comes from A[ids[rowBase+r]].
// ADD_EMBED: C[row][col] += embed[ids[row]][col]  (embed row stride == N).
// ---------------------------------------------------------------------------
template<int K, int N, bool GATHER_A, bool ADD_EMBED>
__global__ __launch_bounds__(256)
void gemm_kt(const float* __restrict__ A, const float* __restrict__ B,
             const int* __restrict__ ids, const float* __restrict__ embed,
             float* __restrict__ C)
{
    constexpr int BM = 128, BN = 128, BK = 16;
    __shared__ __align__(16) float As[BK][BM + 4];
    __shared__ __align__(16) float Bs[BK][BN + 4];
    __shared__ int sIds[BM];

    const int tid = threadIdx.x;
    const int rowBase = blockIdx.x * BM;
    const int colBase = blockIdx.y * BN;

    if (GATHER_A || ADD_EMBED) {
        if (tid < BM) sIds[tid] = ids[rowBase + tid];
        __syncthreads();
    }

    const int ty = tid >> 4;   // 0..15
    const int tx = tid & 15;   // 0..15

    float acc[8][8];
    #pragma unroll
    for (int i = 0; i < 8; i++)
        #pragma unroll
        for (int j = 0; j < 8; j++) acc[i][j] = 0.f;

    for (int k0 = 0; k0 < K; k0 += BK) {
        // Stage A and B tiles (transposed into [k][row] layout).
        // 128 rows x 16 k = 512 float4s each; 256 threads -> 2 each.
        #pragma unroll
        for (int u = 0; u < 2; u++) {
            const int idx = tid + u * 256;
            const int r = idx >> 2;       // 0..127
            const int c = idx & 3;        // float4 slot 0..3 within the 16-wide k tile
            const size_t arow = GATHER_A ? (size_t)sIds[r] : (size_t)(rowBase + r);
            const float4 va = *reinterpret_cast<const float4*>(A + arow * K + k0 + c * 4);
            As[c * 4 + 0][r] = va.x; As[c * 4 + 1][r] = va.y;
            As[c * 4 + 2][r] = va.z; As[c * 4 + 3][r] = va.w;
            const float4 vb = *reinterpret_cast<const float4*>(B + (size_t)(colBase + r) * K + k0 + c * 4);
            Bs[c * 4 + 0][r] = vb.x; Bs[c * 4 + 1][r] = vb.y;
            Bs[c * 4 + 2][r] = vb.z; Bs[c * 4 + 3][r] = vb.w;
        }
        __syncthreads();

        #pragma unroll
        for (int k = 0; k < BK; k++) {
            float a[8], b[8];
            *reinterpret_cast<float4*>(&a[0]) = *reinterpret_cast<const float4*>(&As[k][ty * 8]);
            *reinterpret_cast<float4*>(&a[4]) = *reinterpret_cast<const float4*>(&As[k][ty * 8 + 4]);
            *reinterpret_cast<float4*>(&b[0]) = *reinterpret_cast<const float4*>(&Bs[k][tx * 8]);
            *reinterpret_cast<float4*>(&b[4]) = *reinterpret_cast<const float4*>(&Bs[k][tx * 8 + 4]);
            #pragma unroll
            for (int i = 0; i < 8; i++)
                #pragma unroll
                for (int j = 0; j < 8; j++)
                    acc[i][j] = fmaf(a[i], b[j], acc[i][j]);
        }
        __syncthreads();
    }

    // Epilogue: optional embed add, then float4 stores.
    #pragma unroll
    for (int i = 0; i < 8; i++) {
        const int row = rowBase + ty * 8 + i;
        float* dst = C + (size_t)row * N + colBase + tx * 8;
        float4 c0 = make_float4(acc[i][0], acc[i][1], acc[i][2], acc[i][3]);
        float4 c1 = make_float4(acc[i][4], acc[i][5], acc[i][6], acc[i][7]);
        if (ADD_EMBED) {
            const float* e = embed + (size_t)sIds[ty * 8 + i] * N + colBase + tx * 8;
            const float4 e0 = *reinterpret_cast<const float4*>(e);
            const float4 e1 = *reinterpret_cast<const float4*>(e + 4);
            c0.x += e0.x; c0.y += e0.y; c0.z += e0.z; c0.w += e0.w;
            c1.x += e1.x; c1.y += e1.y; c1.z += e1.z; c1.w += e1.w;
        }
        *reinterpret_cast<float4*>(dst)     = c0;
        *reinterpret_cast<float4*>(dst + 4) = c1;
    }
}

// ---------------------------------------------------------------------------
// In-place LayerNorm + ELU over rows of H [TOKENS][512].
// One block of 128 threads per row, 4 elements (one float4) per thread.
// ---------------------------------------------------------------------------
__global__ __launch_bounds__(128)
void ln_elu_kernel(float* __restrict__ H,
                   const float* __restrict__ ln_w,
                   const float* __restrict__ ln_b)
{
    const int row = blockIdx.x;
    const int tid = threadIdx.x;
    float* x = H + (size_t)row * D_HID + tid * 4;
    const float4 v = *reinterpret_cast<const float4*>(x);

    float s  = v.x + v.y + v.z + v.w;
    float ss = v.x * v.x + v.y * v.y + v.z * v.z + v.w * v.w;
    #pragma unroll
    for (int off = 32; off > 0; off >>= 1) {
        s  += __shfl_down(s, off);
        ss += __shfl_down(ss, off);
    }
    __shared__ float red[4];
    if ((tid & 63) == 0) {
        red[(tid >> 6) * 2 + 0] = s;
        red[(tid >> 6) * 2 + 1] = ss;
    }
    __syncthreads();
    const float sum   = red[0] + red[2];
    const float sumsq = red[1] + red[3];
    const float mu  = sum * (1.f / D_HID);
    const float var = sumsq * (1.f / D_HID) - mu * mu;
    const float rstd = rsqrtf(var + 1e-5f);

    const float4 w = *reinterpret_cast<const float4*>(ln_w + tid * 4);
    const float4 b = *reinterpret_cast<const float4*>(ln_b + tid * 4);

    float y[4] = { (v.x - mu) * rstd * w.x + b.x,
                   (v.y - mu) * rstd * w.y + b.y,
                   (v.z - mu) * rstd * w.z + b.z,
                   (v.w - mu) * rstd * w.w + b.w };
    #pragma unroll
    for (int j = 0; j < 4; j++)
        y[j] = y[j] > 0.f ? y[j] : expm1f(y[j]);

    float4 o = make_float4(y[0], y[1], y[2], y[3]);
    *reinterpret_cast<float4*>(x) = o;
}

extern "C" void kernel_launch(void* const* d_in, const int* in_sizes, int n_in,
                              void* d_out, int out_size, void* d_ws, size_t ws_size,
                              hipStream_t stream)
{
    const float* real  = (const float*)d_in[0];   // [32000, 768]
    const float* embed = (const float*)d_in[1];   // [32000, 4096]
    const float* w1    = (const float*)d_in[2];   // [512, 768]
    const float* w2    = (const float*)d_in[3];   // [4096, 512]
    const float* ln_w  = (const float*)d_in[4];   // [512]
    const float* ln_b  = (const float*)d_in[5];   // [512]
    const int*   ids   = (const int*)d_in[6];     // [8192]
    float* out = (float*)d_out;                   // [8192, 4096]
    float* H   = (float*)d_ws;                    // [8192, 512] fp32 = 16 MB

    // GEMM1: H[t][j] = dot(real[ids[t]], w1[j])   M=8192 N=512 K=768
    dim3 g1(TOKENS / 128, D_HID / 128);
    gemm_kt<D_REAL, D_HID, true, false><<<g1, 256, 0, stream>>>(real, w1, ids, nullptr, H);

    // LN + ELU in place on H
    ln_elu_kernel<<<TOKENS, 128, 0, stream>>>(H, ln_w, ln_b);

    // GEMM2: out[t][m] = dot(H[t], w2[m]) + embed[ids[t]][m]   M=8192 N=4096 K=512
    dim3 g2(TOKENS / 128, D_MODEL / 128);
    gemm_kt<D_HID, D_MODEL, false, true><<<g2, 256, 0, stream>>>(H, w2, ids, embed, out);
}

// Round 2
// 136.341 us; speedup vs baseline: 3.9118x; 3.9118x over previous
//
#include <hip/hip_runtime.h>
#include <hip/hip_bf16.h>
#include <math.h>

#define TOKENS 8192
#define D_REAL 768
#define D_HID  512
#define D_MODEL 4096

typedef __attribute__((ext_vector_type(8))) short bf16x8;   // 8 bf16 in 4 VGPRs
typedef __attribute__((ext_vector_type(4))) float f32x4;    // MFMA accumulator

// fp32 -> bf16, round-to-nearest-even
__device__ inline unsigned short f2bf(float f) {
    union { float f; unsigned u; } v; v.f = f;
    unsigned r = v.u + 0x7FFFu + ((v.u >> 16) & 1u);
    return (unsigned short)(r >> 16);
}
__device__ inline float bf2f(unsigned short h) {
    union { unsigned u; float f; } v; v.u = ((unsigned)h) << 16;
    return v.f;
}

// async global->LDS, 16B per lane. LDS dest = wave-uniform base + lane*16.
__device__ inline void gload_lds16(const void* g, void* lds_wave_base) {
    __builtin_amdgcn_global_load_lds(
        (const __attribute__((address_space(1))) unsigned*)g,
        (__attribute__((address_space(3))) unsigned*)lds_wave_base,
        16, 0, 0);
}

// ---------------------------------------------------------------------------
// bf16 MFMA GEMM (m97 structure): C[M,N] = A[M,K] * B[N,K]^T
// 128x128 tile, BK=32, 256 threads = 4 waves (2x2), each wave 64x64 = 4x4
// fragments of 16x16x32. A,B bf16 K-major; C fp32 (+embed gather) or bf16.
// ---------------------------------------------------------------------------
template<int K, int N, bool ADD_EMBED, bool OUT_BF16>
__global__ __launch_bounds__(256)
void gemm_mfma(const unsigned short* __restrict__ A,
               const unsigned short* __restrict__ B,
               const int* __restrict__ ids,
               const float* __restrict__ embed,
               void* __restrict__ Cout)
{
    __shared__ __align__(16) unsigned short As[128 * 32];
    __shared__ __align__(16) unsigned short Bs[128 * 32];
    __shared__ int sIds[128];

    const int tid = threadIdx.x;
    const int rowBase = blockIdx.x * 128;
    const int colBase = blockIdx.y * 128;

    if (ADD_EMBED && tid < 128) sIds[tid] = ids[rowBase + tid];

    // staging: thread t loads 8 bf16 (16B) from row (t>>2), k-slot (t&3)*8;
    // second iteration covers rows 64..127 (LDS byte offset +4096).
    const int srow = tid >> 2;
    const int scol = (tid & 3) * 8;
    const unsigned short* gA = A + (size_t)(rowBase + srow) * K + scol;
    const unsigned short* gB = B + (size_t)(colBase + srow) * K + scol;
    unsigned short* lA = As + (tid >> 6) * 512;   // wave-uniform base (1024B/wave)
    unsigned short* lB = Bs + (tid >> 6) * 512;

    const int lane = tid & 63;
    const int wv   = tid >> 6;
    const int wm   = (wv >> 1) * 64;   // wave row offset in tile
    const int wn   = (wv & 1) * 64;    // wave col offset in tile
    const int frow = lane & 15;        // fragment row (A/B operand)
    const int fk   = (lane >> 4) * 8;  // fragment k offset

    f32x4 acc[4][4];
    #pragma unroll
    for (int i = 0; i < 4; i++)
        #pragma unroll
        for (int j = 0; j < 4; j++) acc[i][j] = (f32x4)0.f;

    for (int k0 = 0; k0 < K; k0 += 32) {
        gload_lds16(gA,                lA);
        gload_lds16(gA + (size_t)64*K, lA + 2048);
        gload_lds16(gB,                lB);
        gload_lds16(gB + (size_t)64*K, lB + 2048);
        gA += 32; gB += 32;
        __syncthreads();

        bf16x8 af[4], bg[4];
        #pragma unroll
        for (int i = 0; i < 4; i++)
            af[i] = *reinterpret_cast<const bf16x8*>(&As[(wm + i*16 + frow) * 32 + fk]);
        #pragma unroll
        for (int j = 0; j < 4; j++)
            bg[j] = *reinterpret_cast<const bf16x8*>(&Bs[(wn + j*16 + frow) * 32 + fk]);

        #pragma unroll
        for (int i = 0; i < 4; i++)
            #pragma unroll
            for (int j = 0; j < 4; j++)
                acc[i][j] = __builtin_amdgcn_mfma_f32_16x16x32_bf16(af[i], bg[j], acc[i][j], 0, 0, 0);
        __syncthreads();
    }

    // Epilogue. C/D frag: row = (lane>>4)*4 + r, col = lane&15.
    const int orow0 = wm + (lane >> 4) * 4;
    const int ocol0 = wn + frow;
    #pragma unroll
    for (int i = 0; i < 4; i++) {
        #pragma unroll
        for (int r = 0; r < 4; r++) {
            const int lrow = orow0 + i * 16 + r;
            const size_t grow = (size_t)(rowBase + lrow);
            if (OUT_BF16) {
                unsigned short* C = (unsigned short*)Cout;
                #pragma unroll
                for (int j = 0; j < 4; j++)
                    C[grow * N + colBase + ocol0 + j * 16] = f2bf(acc[i][j][r]);
            } else {
                float* C = (float*)Cout;
                const float* e = ADD_EMBED
                    ? embed + (size_t)sIds[lrow] * N + colBase + ocol0 : nullptr;
                #pragma unroll
                for (int j = 0; j < 4; j++) {
                    float v = acc[i][j][r];
                    if (ADD_EMBED) v += e[j * 16];
                    C[grow * N + colBase + ocol0 + j * 16] = v;
                }
            }
        }
    }
}

// ---------------------------------------------------------------------------
// fp32 -> bf16 bulk convert (float4 -> 4x bf16 per thread)
// ---------------------------------------------------------------------------
__global__ __launch_bounds__(256)
void convert_bf16(const float* __restrict__ src, unsigned short* __restrict__ dst, int n4)
{
    const int i = blockIdx.x * 256 + threadIdx.x;
    if (i >= n4) return;
    const float4 v = reinterpret_cast<const float4*>(src)[i];
    ushort4 o;
    o.x = f2bf(v.x); o.y = f2bf(v.y); o.z = f2bf(v.z); o.w = f2bf(v.w);
    reinterpret_cast<ushort4*>(dst)[i] = o;
}

// ---------------------------------------------------------------------------
// Gather rows of real[ids[t]] -> bf16 Ag[t]. One block (192 thr) per token.
// ---------------------------------------------------------------------------
__global__ __launch_bounds__(192)
void gather_bf16(const float* __restrict__ real, const int* __restrict__ ids,
                 unsigned short* __restrict__ Ag)
{
    const int row = blockIdx.x;
    const int t = threadIdx.x;
    const float4 v = *reinterpret_cast<const float4*>(real + (size_t)ids[row] * D_REAL + t * 4);
    ushort4 o;
    o.x = f2bf(v.x); o.y = f2bf(v.y); o.z = f2bf(v.z); o.w = f2bf(v.w);
    *reinterpret_cast<ushort4*>(Ag + (size_t)row * D_REAL + t * 4) = o;
}

// ---------------------------------------------------------------------------
// In-place LayerNorm + ELU on bf16 H [TOKENS][512]. One wave per row,
// 8 bf16 per lane, f32 stats via shuffle reduce.
// ---------------------------------------------------------------------------
__global__ __launch_bounds__(256)
void ln_elu_bf16(unsigned short* __restrict__ H,
                 const float* __restrict__ ln_w, const float* __restrict__ ln_b)
{
    const int row = blockIdx.x * 4 + (threadIdx.x >> 6);
    const int t = threadIdx.x & 63;
    unsigned short* x = H + (size_t)row * D_HID + t * 8;

    bf16x8 v = *reinterpret_cast<const bf16x8*>(x);
    float f[8], s = 0.f, ss = 0.f;
    #pragma unroll
    for (int j = 0; j < 8; j++) {
        f[j] = bf2f((unsigned short)v[j]);
        s += f[j]; ss += f[j] * f[j];
    }
    #pragma unroll
    for (int off = 32; off > 0; off >>= 1) {
        s  += __shfl_down(s, off);
        ss += __shfl_down(ss, off);
    }
    s = __shfl(s, 0); ss = __shfl(ss, 0);
    const float mu = s * (1.f / D_HID);
    const float var = ss * (1.f / D_HID) - mu * mu;
    const float rstd = rsqrtf(var + 1e-5f);

    const float4 w0 = *reinterpret_cast<const float4*>(ln_w + t * 8);
    const float4 w1 = *reinterpret_cast<const float4*>(ln_w + t * 8 + 4);
    const float4 b0 = *reinterpret_cast<const float4*>(ln_b + t * 8);
    const float4 b1 = *reinterpret_cast<const float4*>(ln_b + t * 8 + 4);
    const float wa[8] = { w0.x, w0.y, w0.z, w0.w, w1.x, w1.y, w1.z, w1.w };
    const float ba[8] = { b0.x, b0.y, b0.z, b0.w, b1.x, b1.y, b1.z, b1.w };

    bf16x8 o;
    #pragma unroll
    for (int j = 0; j < 8; j++) {
        float y = (f[j] - mu) * rstd * wa[j] + ba[j];
        y = y > 0.f ? y : expm1f(y);
        o[j] = (short)f2bf(y);
    }
    *reinterpret_cast<bf16x8*>(x) = o;
}

extern "C" void kernel_launch(void* const* d_in, const int* in_sizes, int n_in,
                              void* d_out, int out_size, void* d_ws, size_t ws_size,
                              hipStream_t stream)
{
    const float* real  = (const float*)d_in[0];   // [32000, 768]
    const float* embed = (const float*)d_in[1];   // [32000, 4096]
    const float* w1    = (const float*)d_in[2];   // [512, 768]
    const float* w2    = (const float*)d_in[3];   // [4096, 512]
    const float* ln_w  = (const float*)d_in[4];   // [512]
    const float* ln_b  = (const float*)d_in[5];   // [512]
    const int*   ids   = (const int*)d_in[6];     // [8192]
    float* out = (float*)d_out;                   // [8192, 4096] fp32

    // ws layout (13.4 MB total; 16 MB known available):
    unsigned short* Hb  = (unsigned short*)d_ws;                 // [8192][512] bf16
    unsigned short* w1b = Hb  + (size_t)TOKENS * D_HID;          // [512][768]  bf16
    unsigned short* w2b = w1b + (size_t)D_HID * D_REAL;          // [4096][512] bf16
    // d_out doubles as scratch for the gathered bf16 A (12.6 MB) — it is
    // fully overwritten by GEMM2 afterwards.
    unsigned short* Ag  = (unsigned short*)d_out;                // [8192][768] bf16

    convert_bf16<<<(D_HID * D_REAL / 4 + 255) / 256, 256, 0, stream>>>(w1, w1b, D_HID * D_REAL / 4);
    convert_bf16<<<(D_MODEL * D_HID / 4 + 255) / 256, 256, 0, stream>>>(w2, w2b, D_MODEL * D_HID / 4);
    gather_bf16<<<TOKENS, 192, 0, stream>>>(real, ids, Ag);

    // GEMM1: Hb = Ag * w1^T   (M=8192, N=512, K=768), bf16 out
    dim3 g1(TOKENS / 128, D_HID / 128);
    gemm_mfma<D_REAL, D_HID, false, true><<<g1, 256, 0, stream>>>(Ag, w1b, nullptr, nullptr, Hb);

    ln_elu_bf16<<<TOKENS / 4, 256, 0, stream>>>(Hb, ln_w, ln_b);

    // GEMM2: out = Hb * w2^T + embed[ids]   (M=8192, N=4096, K=512), fp32 out
    dim3 g2(TOKENS / 128, D_MODEL / 128);
    gemm_mfma<D_HID, D_MODEL, true, false><<<g2, 256, 0, stream>>>(Hb, w2b, ids, embed, out);
}